// Round 5
// baseline (266.998 us; speedup 1.0000x reference)
//
#include <hip/hip_runtime.h>
#include <hip/hip_bf16.h>
#include <math.h>

#define NRAYS 32768
#define NMULTI 6
#define TOTAL_PARAMS 14995560

typedef __attribute__((ext_vector_type(8))) short short8v;
typedef __attribute__((ext_vector_type(4))) float float4v;

__device__ __forceinline__ float sigmoidf_(float v) { return 1.0f / (1.0f + expf(-v)); }
__device__ __forceinline__ short f2bf(float v) {
    __hip_bfloat16 b = __float2bfloat16(v);
    return *reinterpret_cast<short*>(&b);
}
__device__ __forceinline__ float bfbits2f(unsigned u16) {
    unsigned u = u16 << 16;
    return *reinterpret_cast<float*>(&u);
}

// ---------------------------------------------------------------------------
// Streaming f32 -> bf16 table conversion (nontemporal src read to keep the
// bf16 copy L3-resident across graph replays).
// ---------------------------------------------------------------------------
__global__ __launch_bounds__(256) void conv_tab(
    const float* __restrict__ src, short* __restrict__ dst, int n8)
{
    int i = blockIdx.x * 256 + threadIdx.x;
    const int stride = gridDim.x * 256;
    for (; i < n8; i += stride) {
        const float4v* s4 = (const float4v*)src + (size_t)i * 2;
        float4v a = __builtin_nontemporal_load(s4);
        float4v b = __builtin_nontemporal_load(s4 + 1);
        short8v o;
        o[0] = f2bf(a.x); o[1] = f2bf(a.y); o[2] = f2bf(a.z); o[3] = f2bf(a.w);
        o[4] = f2bf(b.x); o[5] = f2bf(b.y); o[6] = f2bf(b.z); o[7] = f2bf(b.w);
        *((short8v*)dst + i) = o;
    }
}

// ---------------------------------------------------------------------------
// Pack f32 weights [K x 256] into MFMA B-fragment-major bf16
// ---------------------------------------------------------------------------
__global__ void pack_w(const float* __restrict__ src, short* __restrict__ dst,
                       int K, int total)
{
    int o = blockIdx.x * 256 + threadIdx.x;
    if (o >= total) return;
    int e = o & 7, lane = (o >> 3) & 63, nt = (o >> 9) & 15, ks = o >> 13;
    int k = ks * 32 + ((lane >> 4) << 3) + e;
    int n = nt * 16 + (lane & 15);
    float v = (k < K) ? src[k * 256 + n] : 0.0f;
    dst[o] = f2bf(v);
}

// ---------------------------------------------------------------------------
// Encode 5 levels starting at L0 for one point; atomicAdd into fsum.
// BF=true: gather from bf16 table (uint2/corner); else f32 (float4/corner).
// ---------------------------------------------------------------------------
template<int L0, bool BF>
__device__ __forceinline__ void encode5(
    float ux, float uy, float uz, float s,
    const void* __restrict__ tab, float (*fsum)[40], int ray_l)
{
    constexpr int RES[10] = {16, 32, 64, 128, 256, 512, 1024, 2048, 4096, 8192};
    constexpr int OFF[10] = {0, 4920, 40864, 315496, 2412648, 4509800,
                             6606952, 8704104, 10801256, 12898408};
    #pragma unroll
    for (int i = 0; i < 5; ++i) {
        const int l = L0 + i;
        const float Rf = (float)RES[l];
        const float wl = erff(1.0f / fmaxf(2.8284271247461903f * s * Rf, 1e-10f));
        if (wl < 0.02f) continue;     // skip bound: wl*0.1 = 2e-3 per feature

        float px = ux * (Rf - 1.0f) + 0.5f;
        float py = uy * (Rf - 1.0f) + 0.5f;
        float pz = uz * (Rf - 1.0f) + 0.5f;
        float fpx = floorf(px), fpy = floorf(py), fpz = floorf(pz);
        float fx = px - fpx, fy = py - fpy, fz = pz - fpz;
        unsigned ix = (unsigned)fpx, iy = (unsigned)fpy, iz = (unsigned)fpz;

        float wx[2] = {1.0f - fx, fx};
        float wy[2] = {1.0f - fy, fy};
        float wz[2] = {1.0f - fz, fz};
        unsigned ox[2], oy[2], oz[2];
        if (l < 3) {                       // dense levels
            unsigned S = (unsigned)RES[l] + 1u;
            ox[0] = ix;          ox[1] = ix + 1u;
            oy[0] = iy * S;      oy[1] = oy[0] + S;
            oz[0] = iz * S * S;  oz[1] = oz[0] + S * S;
        } else {                           // hashed levels, params = 2^21
            ox[0] = ix;                    ox[1] = ix + 1u;
            oy[0] = iy * 2654435761u;      oy[1] = oy[0] + 2654435761u;
            oz[0] = iz * 805459861u;       oz[1] = oz[0] + 805459861u;
        }

        float ax = 0.f, ay = 0.f, az = 0.f, aw = 0.f;
        #pragma unroll
        for (int c = 0; c < 8; ++c) {
            const int bx = (c >> 2) & 1, by = (c >> 1) & 1, bz = c & 1;
            unsigned idx;
            if (l < 3) idx = ox[bx] + oy[by] + oz[bz];
            else       idx = (ox[bx] ^ oy[by] ^ oz[bz]) & 0x1FFFFFu;
            const float w = wx[bx] * wy[by] * wz[bz];
            float ex, ey, ez, ew;
            if constexpr (BF) {
                uint2 e = ((const uint2*)tab)[OFF[l] + (int)idx];
                ex = bfbits2f(e.x & 0xFFFFu); ey = bfbits2f(e.x >> 16);
                ez = bfbits2f(e.y & 0xFFFFu); ew = bfbits2f(e.y >> 16);
            } else {
                float4 e = ((const float4*)tab)[OFF[l] + (int)idx];
                ex = e.x; ey = e.y; ez = e.z; ew = e.w;
            }
            ax += w * ex; ay += w * ey; az += w * ez; aw += w * ew;
        }
        atomicAdd(&fsum[ray_l][l * 4 + 0], ax * wl);
        atomicAdd(&fsum[ray_l][l * 4 + 1], ay * wl);
        atomicAdd(&fsum[ray_l][l * 4 + 2], az * wl);
        atomicAdd(&fsum[ray_l][l * 4 + 3], aw * wl);
    }
}

// ---------------------------------------------------------------------------
// Kernel A: contraction + hash-grid encode + erf-weighted mean over samples.
// Block = 768 threads (12 waves) = 384 points x 2 level-halves (64 rays).
// ---------------------------------------------------------------------------
template<bool BF>
__global__ __launch_bounds__(768) void enc_kernel(
    const float* __restrict__ means, const float* __restrict__ stds,
    const void* __restrict__ tab, float* __restrict__ features)
{
    __shared__ float fsum[64][40];
    const int tid  = threadIdx.x;
    const int lane = tid & 63;
    const int wv   = tid >> 6;            // 0..11
    const int half = wv & 1;              // 0: levels 0-4, 1: levels 5-9
    const int pidx = (wv >> 1) * 64 + lane;      // 0..383 point within block
    const int ray_l = pidx / 6;
    const int p    = blockIdx.x * 384 + pidx;    // global point

    for (int i = tid; i < 64 * 40; i += 768) (&fsum[0][0])[i] = 0.0f;
    __syncthreads();

    const float mx = means[p * 3 + 0], my = means[p * 3 + 1], mz = means[p * 3 + 2];
    const float sd = stds[p];

    // mipnerf360 contraction + std scaling
    float r2 = fmaxf(mx * mx + my * my + mz * mz, 1.1920929e-07f);
    float rr = sqrtf(r2);
    float zx, zy, zz, s;
    if (r2 <= 1.0f) { zx = mx; zy = my; zz = mz; s = sd; }
    else {
        float sc = (2.0f * rr - 1.0f) / r2;
        zx = mx * sc; zy = my * sc; zz = mz * sc;
        float det = (1.0f / r2) * sc * sc;
        s = sd * cbrtf(det);
    }
    zx *= 0.5f; zy *= 0.5f; zz *= 0.5f; s *= 0.5f;   // bound = 2
    const float ux = fminf(fmaxf((zx + 1.0f) * 0.5f, 0.0f), 1.0f);
    const float uy = fminf(fmaxf((zy + 1.0f) * 0.5f, 0.0f), 1.0f);
    const float uz = fminf(fmaxf((zz + 1.0f) * 0.5f, 0.0f), 1.0f);

    if (half == 0) encode5<0, BF>(ux, uy, uz, s, tab, fsum, ray_l);
    else           encode5<5, BF>(ux, uy, uz, s, tab, fsum, ray_l);
    __syncthreads();

    const float inv6 = 1.0f / 6.0f;
    for (int i = tid; i < 64 * 40; i += 768)
        features[blockIdx.x * 64 * 40 + i] = (&fsum[0][0])[i] * inv6;
}

// ---------------------------------------------------------------------------
// Kernel B: density MLP  features[64,40] -> h0[64] -> x[256] (bf16 out)
// ---------------------------------------------------------------------------
__global__ __launch_bounds__(256) void dens_kernel(
    const float* __restrict__ features,
    const float* __restrict__ dw0, const float* __restrict__ db0,
    const float* __restrict__ dw1, const float* __restrict__ db1,
    short* __restrict__ x_out, float* __restrict__ dens_out)
{
    __shared__ __align__(16) float feat_s[64][40];
    __shared__ __align__(16) float h0_s[64][64];
    const int tid  = threadIdx.x;
    const int ray0 = blockIdx.x * 64;

    for (int i = tid; i < 64 * 40; i += 256)
        (&feat_s[0][0])[i] = features[ray0 * 40 + i];
    __syncthreads();

    {   // layer 0: 40 -> 64, relu
        const int nn = tid & 63;
        const int q  = tid >> 6;
        float wk[40];
        #pragma unroll
        for (int k = 0; k < 40; ++k) wk[k] = dw0[k * 64 + nn];
        const float b = db0[nn];
        #pragma unroll 2
        for (int r = q * 16; r < q * 16 + 16; ++r) {
            float acc = b;
            #pragma unroll
            for (int k = 0; k < 40; ++k) acc += wk[k] * feat_s[r][k];
            h0_s[r][nn] = fmaxf(acc, 0.0f);
        }
    }
    __syncthreads();

    {   // layer 1: 64 -> 256; density = softplus(x0 - 1)
        const int nn = tid;
        float wk[64];
        #pragma unroll
        for (int k = 0; k < 64; ++k) wk[k] = dw1[k * 256 + nn];
        const float b = db1[nn];
        #pragma unroll 2
        for (int r = 0; r < 64; ++r) {
            float acc = b;
            #pragma unroll
            for (int k = 0; k < 64; ++k) acc += wk[k] * h0_s[r][k];
            x_out[(size_t)(ray0 + r) * 256 + nn] = f2bf(acc);
            if (nn == 0) {
                float z = acc - 1.0f;
                dens_out[ray0 + r] = fmaxf(z, 0.0f) + log1pf(expf(-fabsf(z)));
            }
        }
    }
}

// ---------------------------------------------------------------------------
// Kernel C: rgb branch via MFMA. 64 rays/block, 4 waves, wave = 16-ray m-tile.
// LDS row layout (bf16, stride 552): [y1(0..255) | x(256..511) | dir(512..538) | 0]
// ---------------------------------------------------------------------------
__global__ __launch_bounds__(256, 2) void rgb_mfma(
    const short* __restrict__ x_bf, const float* __restrict__ viewdirs,
    const short* __restrict__ w0p, const float* __restrict__ sb0,
    const short* __restrict__ w1p, const float* __restrict__ sb1,
    const float* __restrict__ rw,  const float* __restrict__ rb,
    float* __restrict__ out)
{
    __shared__ __align__(16) short inp_s[64][552];
    const int tid  = threadIdx.x;
    const int lane = tid & 63;
    const int wv   = tid >> 6;              // wave id = m-tile
    const int ray0 = blockIdx.x * 64;

    {   // x part -> cols 256..511 (short8 copies)
        const short8v* xg = (const short8v*)x_bf;
        for (int i = tid; i < 64 * 32; i += 256) {
            int r = i >> 5, c = i & 31;
            *(short8v*)&inp_s[r][256 + c * 8] = xg[(size_t)(ray0 + r) * 32 + c];
        }
    }
    for (int i = tid; i < 64 * 27; i += 256) {   // dir enc -> cols 512..538
        int r = i / 27, q = i % 27;
        const float* vd = &viewdirs[(size_t)(ray0 + r) * 3];
        float v;
        if (q < 3)       v = vd[q];
        else if (q < 15) { int ii = q - 3;  v = sinf(vd[ii % 3] * (float)(1 << (ii / 3))); }
        else             { int ii = q - 15; v = cosf(vd[ii % 3] * (float)(1 << (ii / 3))); }
        inp_s[r][512 + q] = f2bf(v);
    }
    for (int i = tid; i < 64 * 13; i += 256) {   // zero pad cols 539..551
        int r = i / 13, c = i % 13;
        inp_s[r][539 + c] = 0;
    }
    __syncthreads();

    const int arow  = wv * 16 + (lane & 15);
    const int kseg  = (lane >> 4) * 8;
    const int crow0 = wv * 16 + (lane >> 4) * 4;
    const int ccol  = lane & 15;
    const short8v* w0f = (const short8v*)w0p;
    const short8v* w1f = (const short8v*)w1p;

    float4v acc[16];

    // ---- GEMM1: y1 = relu(inp @ sw0 + sb0), K = 288 (9 k-steps)
    #pragma unroll
    for (int nt = 0; nt < 16; ++nt) acc[nt] = (float4v){0.f, 0.f, 0.f, 0.f};
    for (int ks = 0; ks < 9; ++ks) {
        short8v a = *(const short8v*)&inp_s[arow][256 + ks * 32 + kseg];
        #pragma unroll
        for (int nt = 0; nt < 16; ++nt) {
            short8v b = w0f[(ks * 16 + nt) * 64 + lane];
            acc[nt] = __builtin_amdgcn_mfma_f32_16x16x32_bf16(a, b, acc[nt], 0, 0, 0);
        }
    }
    #pragma unroll
    for (int nt = 0; nt < 16; ++nt) {
        float bias = sb0[nt * 16 + ccol];
        #pragma unroll
        for (int j = 0; j < 4; ++j)
            inp_s[crow0 + j][nt * 16 + ccol] = f2bf(fmaxf(acc[nt][j] + bias, 0.0f));
    }
    __syncthreads();

    // ---- GEMM2: y2 = relu([y1,x,dir] @ sw1 + sb1), K = 544 (17 k-steps)
    #pragma unroll
    for (int nt = 0; nt < 16; ++nt) acc[nt] = (float4v){0.f, 0.f, 0.f, 0.f};
    for (int ks = 0; ks < 17; ++ks) {
        short8v a = *(const short8v*)&inp_s[arow][ks * 32 + kseg];
        #pragma unroll
        for (int nt = 0; nt < 16; ++nt) {
            short8v b = w1f[(ks * 16 + nt) * 64 + lane];
            acc[nt] = __builtin_amdgcn_mfma_f32_16x16x32_bf16(a, b, acc[nt], 0, 0, 0);
        }
    }

    // ---- y2 = relu(acc + sb1) in regs; rgb = sigmoid(y2 @ rw + rb)
    float p[4][3];
    #pragma unroll
    for (int j = 0; j < 4; ++j) { p[j][0] = p[j][1] = p[j][2] = 0.f; }
    #pragma unroll
    for (int nt = 0; nt < 16; ++nt) {
        float bias = sb1[nt * 16 + ccol];
        const float* rwn = &rw[(size_t)(nt * 16 + ccol) * 3];
        float r0 = rwn[0], r1 = rwn[1], r2 = rwn[2];
        #pragma unroll
        for (int j = 0; j < 4; ++j) {
            float y = fmaxf(acc[nt][j] + bias, 0.0f);
            p[j][0] += y * r0; p[j][1] += y * r1; p[j][2] += y * r2;
        }
    }
    #pragma unroll
    for (int m = 1; m <= 8; m <<= 1) {
        #pragma unroll
        for (int j = 0; j < 4; ++j) {
            p[j][0] += __shfl_xor(p[j][0], m);
            p[j][1] += __shfl_xor(p[j][1], m);
            p[j][2] += __shfl_xor(p[j][2], m);
        }
    }
    if ((lane & 15) == 0) {
        #pragma unroll
        for (int j = 0; j < 4; ++j) {
            int ray = ray0 + crow0 + j;
            out[NRAYS + ray * 3 + 0] = sigmoidf_(p[j][0] + rb[0]) * 1.002f - 0.001f;
            out[NRAYS + ray * 3 + 1] = sigmoidf_(p[j][1] + rb[1]) * 1.002f - 0.001f;
            out[NRAYS + ray * 3 + 2] = sigmoidf_(p[j][2] + rb[2]) * 1.002f - 0.001f;
        }
    }
}

// ---------------------------------------------------------------------------
extern "C" void kernel_launch(void* const* d_in, const int* in_sizes, int n_in,
                              void* d_out, int out_size, void* d_ws, size_t ws_size,
                              hipStream_t stream)
{
    const float* means    = (const float*)d_in[0];
    const float* stds     = (const float*)d_in[1];
    const float* viewdirs = (const float*)d_in[2];
    const float* emb      = (const float*)d_in[3];
    const float* dw0      = (const float*)d_in[4];
    const float* db0      = (const float*)d_in[5];
    const float* dw1      = (const float*)d_in[6];
    const float* db1      = (const float*)d_in[7];
    const float* sw0      = (const float*)d_in[8];
    const float* sb0      = (const float*)d_in[9];
    const float* sw1      = (const float*)d_in[10];
    const float* sb1      = (const float*)d_in[11];
    const float* rw       = (const float*)d_in[12];
    const float* rb       = (const float*)d_in[13];

    float* out = (float*)d_out;
    char*  ws  = (char*)d_ws;

    // ws layout (bytes)
    float* features = (float*)(ws);                         //  5,242,880
    short* x_bf     = (short*)(ws + 5242880);               // 16,777,216
    short* w0p      = (short*)(ws + 22020096);              //    147,456
    short* w1p      = (short*)(ws + 22167552);              //    278,528
    short* tab_bf   = (short*)(ws + 22446080);              // 119,964,480
    const size_t need_bf = 22446080u + (size_t)TOTAL_PARAMS * 4 * 2;
    const bool use_bf = ws_size >= need_bf;

    pack_w<<<(9 * 16 * 64 * 8 + 255) / 256, 256, 0, stream>>>(sw0, w0p, 283, 9 * 16 * 64 * 8);
    pack_w<<<(17 * 16 * 64 * 8 + 255) / 256, 256, 0, stream>>>(sw1, w1p, 539, 17 * 16 * 64 * 8);

    if (use_bf) {
        const int n8 = TOTAL_PARAMS * 4 / 8;   // 7,497,780 (exact)
        conv_tab<<<4096, 256, 0, stream>>>(emb, tab_bf, n8);
        enc_kernel<true><<<NRAYS / 64, 768, 0, stream>>>(means, stds, tab_bf, features);
    } else {
        enc_kernel<false><<<NRAYS / 64, 768, 0, stream>>>(means, stds, emb, features);
    }
    dens_kernel<<<NRAYS / 64, 256, 0, stream>>>(features, dw0, db0, dw1, db1, x_bf, out);
    rgb_mfma   <<<NRAYS / 64, 256, 0, stream>>>(x_bf, viewdirs, w0p, sb0, w1p, sb1, rw, rb, out);
}

// Round 6
// 183.375 us; speedup vs baseline: 1.4560x; 1.4560x over previous
//
#include <hip/hip_runtime.h>
#include <hip/hip_bf16.h>
#include <math.h>

#define NRAYS 32768
#define NMULTI 6

typedef __attribute__((ext_vector_type(8))) short short8v;
typedef __attribute__((ext_vector_type(4))) float float4v;

__device__ __forceinline__ float sigmoidf_(float v) { return 1.0f / (1.0f + expf(-v)); }
__device__ __forceinline__ short f2bf(float v) {
    __hip_bfloat16 b = __float2bfloat16(v);
    return *reinterpret_cast<short*>(&b);
}

// ---------------------------------------------------------------------------
// Pack all 4 weight matrices into MFMA B-fragment-major bf16 in one kernel.
// frag layout: dst[((ks*NT+nt)*64+lane)*8+e] = W[ks*32+(lane>>4)*8+e][nt*16+(lane&15)]
// ---------------------------------------------------------------------------
__device__ __forceinline__ void pack_one(
    const float* __restrict__ src, short* __restrict__ dst,
    int o, int NT, int N, int K)
{
    int e = o & 7, lane = (o >> 3) & 63;
    int nt = (o >> 9) % NT, ks = o / (512 * NT);
    int k = ks * 32 + ((lane >> 4) << 3) + e;
    int n = nt * 16 + (lane & 15);
    dst[o] = (k < K) ? f2bf(src[k * N + n]) : (short)0;
}

#define PN0 4096      // dw0: K=40 ->2ks, N=64  (4 nt)
#define PN1 16384     // dw1: K=64 ->2ks, N=256 (16 nt)
#define PN2 73728     // sw0: K=283->9ks, N=256
#define PN3 139264    // sw1: K=539->17ks,N=256

__global__ __launch_bounds__(256) void pack4(
    const float* __restrict__ dw0, const float* __restrict__ dw1,
    const float* __restrict__ sw0, const float* __restrict__ sw1,
    short* __restrict__ d0, short* __restrict__ d1,
    short* __restrict__ d2, short* __restrict__ d3)
{
    int o = blockIdx.x * 256 + threadIdx.x;
    if (o < PN0)                   pack_one(dw0, d0, o, 4, 64, 40);
    else if (o < PN0+PN1)          pack_one(dw1, d1, o-PN0, 16, 256, 64);
    else if (o < PN0+PN1+PN2)      pack_one(sw0, d2, o-PN0-PN1, 16, 256, 283);
    else if (o < PN0+PN1+PN2+PN3)  pack_one(sw1, d3, o-PN0-PN1-PN2, 16, 256, 539);
}

// ---------------------------------------------------------------------------
// Encode 5 levels starting at L0 for one point; atomicAdd into fsum.
// ---------------------------------------------------------------------------
template<int L0>
__device__ __forceinline__ void encode5(
    float ux, float uy, float uz, float s,
    const float4* __restrict__ etab, float (*fsum)[40], int ray_l)
{
    constexpr int RES[10] = {16, 32, 64, 128, 256, 512, 1024, 2048, 4096, 8192};
    constexpr int OFF[10] = {0, 4920, 40864, 315496, 2412648, 4509800,
                             6606952, 8704104, 10801256, 12898408};
    #pragma unroll
    for (int i = 0; i < 5; ++i) {
        const int l = L0 + i;
        const float Rf = (float)RES[l];
        const float wl = erff(1.0f / fmaxf(2.8284271247461903f * s * Rf, 1e-10f));
        if (wl < 0.02f) continue;     // skip bound: wl*0.1 = 2e-3 per feature

        float px = ux * (Rf - 1.0f) + 0.5f;
        float py = uy * (Rf - 1.0f) + 0.5f;
        float pz = uz * (Rf - 1.0f) + 0.5f;
        float fpx = floorf(px), fpy = floorf(py), fpz = floorf(pz);
        float fx = px - fpx, fy = py - fpy, fz = pz - fpz;
        unsigned ix = (unsigned)fpx, iy = (unsigned)fpy, iz = (unsigned)fpz;

        float wx[2] = {1.0f - fx, fx};
        float wy[2] = {1.0f - fy, fy};
        float wz[2] = {1.0f - fz, fz};
        unsigned ox[2], oy[2], oz[2];
        if (l < 3) {                       // dense levels
            unsigned S = (unsigned)RES[l] + 1u;
            ox[0] = ix;          ox[1] = ix + 1u;
            oy[0] = iy * S;      oy[1] = oy[0] + S;
            oz[0] = iz * S * S;  oz[1] = oz[0] + S * S;
        } else {                           // hashed levels, params = 2^21
            ox[0] = ix;                    ox[1] = ix + 1u;
            oy[0] = iy * 2654435761u;      oy[1] = oy[0] + 2654435761u;
            oz[0] = iz * 805459861u;       oz[1] = oz[0] + 805459861u;
        }

        float ax = 0.f, ay = 0.f, az = 0.f, aw = 0.f;
        #pragma unroll
        for (int c = 0; c < 8; ++c) {
            const int bx = (c >> 2) & 1, by = (c >> 1) & 1, bz = c & 1;
            unsigned idx;
            if (l < 3) idx = ox[bx] + oy[by] + oz[bz];
            else       idx = (ox[bx] ^ oy[by] ^ oz[bz]) & 0x1FFFFFu;
            const float w = wx[bx] * wy[by] * wz[bz];
            const float4 e = etab[OFF[l] + (int)idx];
            ax += w * e.x; ay += w * e.y; az += w * e.z; aw += w * e.w;
        }
        atomicAdd(&fsum[ray_l][l * 4 + 0], ax * wl);
        atomicAdd(&fsum[ray_l][l * 4 + 1], ay * wl);
        atomicAdd(&fsum[ray_l][l * 4 + 2], az * wl);
        atomicAdd(&fsum[ray_l][l * 4 + 3], aw * wl);
    }
}

// ---------------------------------------------------------------------------
// Kernel A: contraction + hash-grid encode + erf-weighted mean over samples.
// Block = 768 threads (12 waves) = 384 points x 2 level-halves (64 rays).
// Output: bf16 features [NRAYS][40].
// ---------------------------------------------------------------------------
__global__ __launch_bounds__(768) void enc_kernel(
    const float* __restrict__ means, const float* __restrict__ stds,
    const float* __restrict__ emb, short* __restrict__ features)
{
    __shared__ float fsum[64][40];
    const int tid  = threadIdx.x;
    const int lane = tid & 63;
    const int wv   = tid >> 6;            // 0..11
    const int half = wv & 1;              // 0: levels 0-4, 1: levels 5-9
    const int pidx = (wv >> 1) * 64 + lane;      // 0..383 point within block
    const int ray_l = pidx / 6;
    const int p    = blockIdx.x * 384 + pidx;    // global point

    for (int i = tid; i < 64 * 40; i += 768) (&fsum[0][0])[i] = 0.0f;
    __syncthreads();

    const float mx = means[p * 3 + 0], my = means[p * 3 + 1], mz = means[p * 3 + 2];
    const float sd = stds[p];

    // mipnerf360 contraction + std scaling
    float r2 = fmaxf(mx * mx + my * my + mz * mz, 1.1920929e-07f);
    float rr = sqrtf(r2);
    float zx, zy, zz, s;
    if (r2 <= 1.0f) { zx = mx; zy = my; zz = mz; s = sd; }
    else {
        float sc = (2.0f * rr - 1.0f) / r2;
        zx = mx * sc; zy = my * sc; zz = mz * sc;
        float det = (1.0f / r2) * sc * sc;
        s = sd * cbrtf(det);
    }
    zx *= 0.5f; zy *= 0.5f; zz *= 0.5f; s *= 0.5f;   // bound = 2
    const float ux = fminf(fmaxf((zx + 1.0f) * 0.5f, 0.0f), 1.0f);
    const float uy = fminf(fmaxf((zy + 1.0f) * 0.5f, 0.0f), 1.0f);
    const float uz = fminf(fmaxf((zz + 1.0f) * 0.5f, 0.0f), 1.0f);

    const float4* __restrict__ etab = (const float4*)emb;
    if (half == 0) encode5<0>(ux, uy, uz, s, etab, fsum, ray_l);
    else           encode5<5>(ux, uy, uz, s, etab, fsum, ray_l);
    __syncthreads();

    const float inv6 = 1.0f / 6.0f;
    for (int i = tid; i < 64 * 40; i += 768)
        features[blockIdx.x * 64 * 40 + i] = f2bf((&fsum[0][0])[i] * inv6);
}

// ---------------------------------------------------------------------------
// Kernel B: fused MLP (density + rgb) via MFMA.
// Block = 128 threads (2 waves), 64 rays. Wave wv owns rows wv*32..wv*32+31
// (2 m-tiles). Single __syncthreads after staging; all later LDS traffic is
// wave-private rows.
// LDS: feat64[64][64] bf16 (features then h0); inp_s[64][552] bf16:
//      [y1(0..255) | x(256..511) | dir(512..538) | 0-pad(539..551)]
// ---------------------------------------------------------------------------
__global__ __launch_bounds__(128) void mlp_kernel(
    const short* __restrict__ feat_bf, const float* __restrict__ viewdirs,
    const short* __restrict__ dw0p, const float* __restrict__ db0,
    const short* __restrict__ dw1p, const float* __restrict__ db1,
    const short* __restrict__ w0p,  const float* __restrict__ sb0,
    const short* __restrict__ w1p,  const float* __restrict__ sb1,
    const float* __restrict__ rw,   const float* __restrict__ rb,
    float* __restrict__ out)
{
    __shared__ __align__(16) short feat64[64][64];
    __shared__ __align__(16) short inp_s[64][552];
    const int tid  = threadIdx.x;
    const int lane = tid & 63;
    const int wv   = tid >> 6;              // 0 or 1
    const int ray0 = blockIdx.x * 64;

    // ---- stage features (40 cols, pad to 64) ----
    for (int i = tid; i < 64 * 8; i += 128) {
        int r = i >> 3, c8 = i & 7;
        short8v v;
        if (c8 < 5) v = *(const short8v*)&feat_bf[(size_t)(ray0 + r) * 40 + c8 * 8];
        else        v = (short8v){0,0,0,0,0,0,0,0};
        *(short8v*)&feat64[r][c8 * 8] = v;
    }
    // ---- dir enc -> inp_s cols 512..538 ----
    for (int i = tid; i < 64 * 27; i += 128) {
        int r = i / 27, q = i % 27;
        const float* vd = &viewdirs[(size_t)(ray0 + r) * 3];
        float v;
        if (q < 3)       v = vd[q];
        else if (q < 15) { int ii = q - 3;  v = sinf(vd[ii % 3] * (float)(1 << (ii / 3))); }
        else             { int ii = q - 15; v = cosf(vd[ii % 3] * (float)(1 << (ii / 3))); }
        inp_s[r][512 + q] = f2bf(v);
    }
    for (int i = tid; i < 64 * 13; i += 128) {   // zero pad cols 539..551
        int r = i / 13, c = i % 13;
        inp_s[r][539 + c] = 0;
    }
    __syncthreads();   // the only block-wide barrier

    const int rbase = wv * 32;
    const int arow0 = rbase + (lane & 15);       // + mt*16
    const int kseg  = (lane >> 4) * 8;
    const int crow0 = rbase + (lane >> 4) * 4;   // + mt*16 + j
    const int ccol  = lane & 15;
    const short8v* d0f = (const short8v*)dw0p;
    const short8v* d1f = (const short8v*)dw1p;
    const short8v* w0f = (const short8v*)w0p;
    const short8v* w1f = (const short8v*)w1p;

    // ---- density layer 0: feats[.,40->64pad] @ dw0 -> h0[64], relu ----
    {
        float4v a0[2][4];
        #pragma unroll
        for (int mt = 0; mt < 2; ++mt)
            #pragma unroll
            for (int nt = 0; nt < 4; ++nt) a0[mt][nt] = (float4v){0.f,0.f,0.f,0.f};
        #pragma unroll
        for (int ks = 0; ks < 2; ++ks) {
            short8v a[2];
            #pragma unroll
            for (int mt = 0; mt < 2; ++mt)
                a[mt] = *(const short8v*)&feat64[arow0 + mt*16][ks*32 + kseg];
            #pragma unroll
            for (int nt = 0; nt < 4; ++nt) {
                short8v b = d0f[(ks*4 + nt) * 64 + lane];
                #pragma unroll
                for (int mt = 0; mt < 2; ++mt)
                    a0[mt][nt] = __builtin_amdgcn_mfma_f32_16x16x32_bf16(a[mt], b, a0[mt][nt], 0,0,0);
            }
        }
        #pragma unroll
        for (int nt = 0; nt < 4; ++nt) {
            float bias = db0[nt*16 + ccol];
            #pragma unroll
            for (int mt = 0; mt < 2; ++mt)
                #pragma unroll
                for (int j = 0; j < 4; ++j)
                    feat64[crow0 + mt*16 + j][nt*16 + ccol] =
                        f2bf(fmaxf(a0[mt][nt][j] + bias, 0.0f));
        }
    }

    float4v acc[2][16];

    // ---- density layer 1: h0[64] @ dw1 -> x[256]; density = softplus(x0-1) ----
    #pragma unroll
    for (int mt = 0; mt < 2; ++mt)
        #pragma unroll
        for (int nt = 0; nt < 16; ++nt) acc[mt][nt] = (float4v){0.f,0.f,0.f,0.f};
    #pragma unroll
    for (int ks = 0; ks < 2; ++ks) {
        short8v a[2];
        #pragma unroll
        for (int mt = 0; mt < 2; ++mt)
            a[mt] = *(const short8v*)&feat64[arow0 + mt*16][ks*32 + kseg];
        #pragma unroll
        for (int nt = 0; nt < 16; ++nt) {
            short8v b = d1f[(ks*16 + nt) * 64 + lane];
            #pragma unroll
            for (int mt = 0; mt < 2; ++mt)
                acc[mt][nt] = __builtin_amdgcn_mfma_f32_16x16x32_bf16(a[mt], b, acc[mt][nt], 0,0,0);
        }
    }
    #pragma unroll
    for (int nt = 0; nt < 16; ++nt) {
        float bias = db1[nt*16 + ccol];
        #pragma unroll
        for (int mt = 0; mt < 2; ++mt)
            #pragma unroll
            for (int j = 0; j < 4; ++j) {
                float x = acc[mt][nt][j] + bias;
                inp_s[crow0 + mt*16 + j][256 + nt*16 + ccol] = f2bf(x);
                if (nt == 0 && ccol == 0) {
                    float z = x - 1.0f;   // DENSITY_BIAS
                    out[ray0 + crow0 + mt*16 + j] =
                        fmaxf(z, 0.0f) + log1pf(expf(-fabsf(z)));
                }
            }
    }

    // ---- GEMM1: y1 = relu([x,dir] @ sw0 + sb0), K=288 (9 ks) ----
    #pragma unroll
    for (int mt = 0; mt < 2; ++mt)
        #pragma unroll
        for (int nt = 0; nt < 16; ++nt) acc[mt][nt] = (float4v){0.f,0.f,0.f,0.f};
    for (int ks = 0; ks < 9; ++ks) {
        short8v a[2];
        #pragma unroll
        for (int mt = 0; mt < 2; ++mt)
            a[mt] = *(const short8v*)&inp_s[arow0 + mt*16][256 + ks*32 + kseg];
        #pragma unroll
        for (int nt = 0; nt < 16; ++nt) {
            short8v b = w0f[(ks*16 + nt) * 64 + lane];
            #pragma unroll
            for (int mt = 0; mt < 2; ++mt)
                acc[mt][nt] = __builtin_amdgcn_mfma_f32_16x16x32_bf16(a[mt], b, acc[mt][nt], 0,0,0);
        }
    }
    #pragma unroll
    for (int nt = 0; nt < 16; ++nt) {
        float bias = sb0[nt*16 + ccol];
        #pragma unroll
        for (int mt = 0; mt < 2; ++mt)
            #pragma unroll
            for (int j = 0; j < 4; ++j)
                inp_s[crow0 + mt*16 + j][nt*16 + ccol] =
                    f2bf(fmaxf(acc[mt][nt][j] + bias, 0.0f));
    }

    // ---- GEMM2: y2 = relu([y1,x,dir] @ sw1 + sb1), K=544 (17 ks) ----
    #pragma unroll
    for (int mt = 0; mt < 2; ++mt)
        #pragma unroll
        for (int nt = 0; nt < 16; ++nt) acc[mt][nt] = (float4v){0.f,0.f,0.f,0.f};
    for (int ks = 0; ks < 17; ++ks) {
        short8v a[2];
        #pragma unroll
        for (int mt = 0; mt < 2; ++mt)
            a[mt] = *(const short8v*)&inp_s[arow0 + mt*16][ks*32 + kseg];
        #pragma unroll
        for (int nt = 0; nt < 16; ++nt) {
            short8v b = w1f[(ks*16 + nt) * 64 + lane];
            #pragma unroll
            for (int mt = 0; mt < 2; ++mt)
                acc[mt][nt] = __builtin_amdgcn_mfma_f32_16x16x32_bf16(a[mt], b, acc[mt][nt], 0,0,0);
        }
    }

    // ---- epilogue: y2 = relu(acc + sb1); rgb = sigmoid(y2 @ rw + rb) ----
    #pragma unroll
    for (int mt = 0; mt < 2; ++mt) {
        float p[4][3];
        #pragma unroll
        for (int j = 0; j < 4; ++j) { p[j][0] = p[j][1] = p[j][2] = 0.f; }
        #pragma unroll
        for (int nt = 0; nt < 16; ++nt) {
            float bias = sb1[nt*16 + ccol];
            const float* rwn = &rw[(size_t)(nt*16 + ccol) * 3];
            float r0 = rwn[0], r1 = rwn[1], r2 = rwn[2];
            #pragma unroll
            for (int j = 0; j < 4; ++j) {
                float y = fmaxf(acc[mt][nt][j] + bias, 0.0f);
                p[j][0] += y * r0; p[j][1] += y * r1; p[j][2] += y * r2;
            }
        }
        #pragma unroll
        for (int m = 1; m <= 8; m <<= 1) {
            #pragma unroll
            for (int j = 0; j < 4; ++j) {
                p[j][0] += __shfl_xor(p[j][0], m);
                p[j][1] += __shfl_xor(p[j][1], m);
                p[j][2] += __shfl_xor(p[j][2], m);
            }
        }
        if ((lane & 15) == 0) {
            #pragma unroll
            for (int j = 0; j < 4; ++j) {
                int ray = ray0 + crow0 + mt*16 + j;
                out[NRAYS + ray * 3 + 0] = sigmoidf_(p[j][0] + rb[0]) * 1.002f - 0.001f;
                out[NRAYS + ray * 3 + 1] = sigmoidf_(p[j][1] + rb[1]) * 1.002f - 0.001f;
                out[NRAYS + ray * 3 + 2] = sigmoidf_(p[j][2] + rb[2]) * 1.002f - 0.001f;
            }
        }
    }
}

// ---------------------------------------------------------------------------
extern "C" void kernel_launch(void* const* d_in, const int* in_sizes, int n_in,
                              void* d_out, int out_size, void* d_ws, size_t ws_size,
                              hipStream_t stream)
{
    const float* means    = (const float*)d_in[0];
    const float* stds     = (const float*)d_in[1];
    const float* viewdirs = (const float*)d_in[2];
    const float* emb      = (const float*)d_in[3];
    const float* dw0      = (const float*)d_in[4];
    const float* db0      = (const float*)d_in[5];
    const float* dw1      = (const float*)d_in[6];
    const float* db1      = (const float*)d_in[7];
    const float* sw0      = (const float*)d_in[8];
    const float* sb0      = (const float*)d_in[9];
    const float* sw1      = (const float*)d_in[10];
    const float* sb1      = (const float*)d_in[11];
    const float* rw       = (const float*)d_in[12];
    const float* rb       = (const float*)d_in[13];

    float* out = (float*)d_out;
    char*  ws  = (char*)d_ws;

    // ws layout (bytes, 16-aligned)
    short* feat_bf = (short*)(ws);               // 32768*40*2 = 2,621,440
    short* dw0p    = (short*)(ws + 2621440);     //   8,192
    short* dw1p    = (short*)(ws + 2629632);     //  32,768
    short* w0p     = (short*)(ws + 2662400);     // 147,456
    short* w1p     = (short*)(ws + 2809856);     // 278,528   (end 3,088,384)

    pack4<<<(PN0+PN1+PN2+PN3 + 255) / 256, 256, 0, stream>>>(
        dw0, dw1, sw0, sw1, dw0p, dw1p, w0p, w1p);
    enc_kernel<<<NRAYS / 64, 768, 0, stream>>>(means, stds, emb, feat_bf);
    mlp_kernel<<<NRAYS / 64, 128, 0, stream>>>(
        feat_bf, viewdirs, dw0p, db0, dw1p, db1, w0p, sb0, w1p, sb1, rw, rb, out);
}

// Round 7
// 146.506 us; speedup vs baseline: 1.8224x; 1.2516x over previous
//
#include <hip/hip_runtime.h>
#include <hip/hip_bf16.h>
#include <math.h>

#define NRAYS 32768
#define NMULTI 6

typedef __attribute__((ext_vector_type(8))) short short8v;
typedef __attribute__((ext_vector_type(4))) float float4v;

__device__ __forceinline__ float sigmoidf_(float v) { return 1.0f / (1.0f + expf(-v)); }
__device__ __forceinline__ short f2bf(float v) {
    __hip_bfloat16 b = __float2bfloat16(v);
    return *reinterpret_cast<short*>(&b);
}

// ---------------------------------------------------------------------------
// Pack all 4 weight matrices into MFMA B-fragment-major bf16 in one kernel.
// frag layout: dst[((ks*NT+nt)*64+lane)*8+e] = W[ks*32+(lane>>4)*8+e][nt*16+(lane&15)]
// ---------------------------------------------------------------------------
__device__ __forceinline__ void pack_one(
    const float* __restrict__ src, short* __restrict__ dst,
    int o, int NT, int N, int K)
{
    int e = o & 7, lane = (o >> 3) & 63;
    int nt = (o >> 9) % NT, ks = o / (512 * NT);
    int k = ks * 32 + ((lane >> 4) << 3) + e;
    int n = nt * 16 + (lane & 15);
    dst[o] = (k < K) ? f2bf(src[k * N + n]) : (short)0;
}

#define PN0 4096      // dw0: K=40 ->2ks, N=64  (4 nt)
#define PN1 16384     // dw1: K=64 ->2ks, N=256 (16 nt)
#define PN2 73728     // sw0: K=283->9ks, N=256
#define PN3 139264    // sw1: K=539->17ks,N=256

__global__ __launch_bounds__(256) void pack4(
    const float* __restrict__ dw0, const float* __restrict__ dw1,
    const float* __restrict__ sw0, const float* __restrict__ sw1,
    short* __restrict__ d0, short* __restrict__ d1,
    short* __restrict__ d2, short* __restrict__ d3)
{
    int o = blockIdx.x * 256 + threadIdx.x;
    if (o < PN0)                   pack_one(dw0, d0, o, 4, 64, 40);
    else if (o < PN0+PN1)          pack_one(dw1, d1, o-PN0, 16, 256, 64);
    else if (o < PN0+PN1+PN2)      pack_one(sw0, d2, o-PN0-PN1, 16, 256, 283);
    else if (o < PN0+PN1+PN2+PN3)  pack_one(sw1, d3, o-PN0-PN1-PN2, 16, 256, 539);
}

// ---------------------------------------------------------------------------
// Encode 5 levels starting at L0 for one point; atomicAdd into fsum.
// ---------------------------------------------------------------------------
template<int L0>
__device__ __forceinline__ void encode5(
    float ux, float uy, float uz, float s,
    const float4* __restrict__ etab, float (*fsum)[40], int ray_l)
{
    constexpr int RES[10] = {16, 32, 64, 128, 256, 512, 1024, 2048, 4096, 8192};
    constexpr int OFF[10] = {0, 4920, 40864, 315496, 2412648, 4509800,
                             6606952, 8704104, 10801256, 12898408};
    #pragma unroll
    for (int i = 0; i < 5; ++i) {
        const int l = L0 + i;
        const float Rf = (float)RES[l];
        const float wl = erff(1.0f / fmaxf(2.8284271247461903f * s * Rf, 1e-10f));
        if (wl < 0.03f) continue;     // skip bound: wl*0.1 = 3e-3 per feature

        float px = ux * (Rf - 1.0f) + 0.5f;
        float py = uy * (Rf - 1.0f) + 0.5f;
        float pz = uz * (Rf - 1.0f) + 0.5f;
        float fpx = floorf(px), fpy = floorf(py), fpz = floorf(pz);
        float fx = px - fpx, fy = py - fpy, fz = pz - fpz;
        unsigned ix = (unsigned)fpx, iy = (unsigned)fpy, iz = (unsigned)fpz;

        float wx[2] = {1.0f - fx, fx};
        float wy[2] = {1.0f - fy, fy};
        float wz[2] = {1.0f - fz, fz};
        unsigned ox[2], oy[2], oz[2];
        if (l < 3) {                       // dense levels
            unsigned S = (unsigned)RES[l] + 1u;
            ox[0] = ix;          ox[1] = ix + 1u;
            oy[0] = iy * S;      oy[1] = oy[0] + S;
            oz[0] = iz * S * S;  oz[1] = oz[0] + S * S;
        } else {                           // hashed levels, params = 2^21
            ox[0] = ix;                    ox[1] = ix + 1u;
            oy[0] = iy * 2654435761u;      oy[1] = oy[0] + 2654435761u;
            oz[0] = iz * 805459861u;       oz[1] = oz[0] + 805459861u;
        }

        float ax = 0.f, ay = 0.f, az = 0.f, aw = 0.f;
        #pragma unroll
        for (int c = 0; c < 8; ++c) {
            const int bx = (c >> 2) & 1, by = (c >> 1) & 1, bz = c & 1;
            unsigned idx;
            if (l < 3) idx = ox[bx] + oy[by] + oz[bz];
            else       idx = (ox[bx] ^ oy[by] ^ oz[bz]) & 0x1FFFFFu;
            const float w = wx[bx] * wy[by] * wz[bz];
            const float4 e = etab[OFF[l] + (int)idx];
            ax += w * e.x; ay += w * e.y; az += w * e.z; aw += w * e.w;
        }
        atomicAdd(&fsum[ray_l][l * 4 + 0], ax * wl);
        atomicAdd(&fsum[ray_l][l * 4 + 1], ay * wl);
        atomicAdd(&fsum[ray_l][l * 4 + 2], az * wl);
        atomicAdd(&fsum[ray_l][l * 4 + 3], aw * wl);
    }
}

// ---------------------------------------------------------------------------
// Kernel A: contraction + hash-grid encode + erf-weighted mean over samples.
// Block = 768 threads (12 waves) = 384 points x 2 level-halves (64 rays).
// Output: bf16 features [NRAYS][40].
// ---------------------------------------------------------------------------
__global__ __launch_bounds__(768) void enc_kernel(
    const float* __restrict__ means, const float* __restrict__ stds,
    const float* __restrict__ emb, short* __restrict__ features)
{
    __shared__ float fsum[64][40];
    const int tid  = threadIdx.x;
    const int lane = tid & 63;
    const int wv   = tid >> 6;            // 0..11
    const int half = wv & 1;              // 0: levels 0-4, 1: levels 5-9
    const int pidx = (wv >> 1) * 64 + lane;      // 0..383 point within block
    const int ray_l = pidx / 6;
    const int p    = blockIdx.x * 384 + pidx;    // global point

    for (int i = tid; i < 64 * 40; i += 768) (&fsum[0][0])[i] = 0.0f;
    __syncthreads();

    const float mx = means[p * 3 + 0], my = means[p * 3 + 1], mz = means[p * 3 + 2];
    const float sd = stds[p];

    // mipnerf360 contraction + std scaling
    float r2 = fmaxf(mx * mx + my * my + mz * mz, 1.1920929e-07f);
    float rr = sqrtf(r2);
    float zx, zy, zz, s;
    if (r2 <= 1.0f) { zx = mx; zy = my; zz = mz; s = sd; }
    else {
        float sc = (2.0f * rr - 1.0f) / r2;
        zx = mx * sc; zy = my * sc; zz = mz * sc;
        float det = (1.0f / r2) * sc * sc;
        s = sd * cbrtf(det);
    }
    zx *= 0.5f; zy *= 0.5f; zz *= 0.5f; s *= 0.5f;   // bound = 2
    const float ux = fminf(fmaxf((zx + 1.0f) * 0.5f, 0.0f), 1.0f);
    const float uy = fminf(fmaxf((zy + 1.0f) * 0.5f, 0.0f), 1.0f);
    const float uz = fminf(fmaxf((zz + 1.0f) * 0.5f, 0.0f), 1.0f);

    const float4* __restrict__ etab = (const float4*)emb;
    if (half == 0) encode5<0>(ux, uy, uz, s, etab, fsum, ray_l);
    else           encode5<5>(ux, uy, uz, s, etab, fsum, ray_l);
    __syncthreads();

    const float inv6 = 1.0f / 6.0f;
    for (int i = tid; i < 64 * 40; i += 768)
        features[blockIdx.x * 64 * 40 + i] = f2bf((&fsum[0][0])[i] * inv6);
}

// ---------------------------------------------------------------------------
// Kernel B: fused MLP (density + rgb) via MFMA.
// Block = 256 threads (4 waves), 64 rays. Wave wv owns rows wv*16..wv*16+15
// (one 16-row m-tile). Single __syncthreads after staging; all later LDS
// traffic is wave-private rows.
// LDS: feat64[64][64] bf16 (features then h0); inp_s[64][552] bf16:
//      [y1(0..255) | x(256..511) | dir(512..538) | 0-pad(539..551)]
// ---------------------------------------------------------------------------
__global__ __launch_bounds__(256) void mlp_kernel(
    const short* __restrict__ feat_bf, const float* __restrict__ viewdirs,
    const short* __restrict__ dw0p, const float* __restrict__ db0,
    const short* __restrict__ dw1p, const float* __restrict__ db1,
    const short* __restrict__ w0p,  const float* __restrict__ sb0,
    const short* __restrict__ w1p,  const float* __restrict__ sb1,
    const float* __restrict__ rw,   const float* __restrict__ rb,
    float* __restrict__ out)
{
    __shared__ __align__(16) short feat64[64][64];
    __shared__ __align__(16) short inp_s[64][552];
    const int tid  = threadIdx.x;
    const int lane = tid & 63;
    const int wv   = tid >> 6;              // 0..3
    const int ray0 = blockIdx.x * 64;

    // ---- stage features (40 cols, pad to 64) ----
    for (int i = tid; i < 64 * 8; i += 256) {
        int r = i >> 3, c8 = i & 7;
        short8v v;
        if (c8 < 5) v = *(const short8v*)&feat_bf[(size_t)(ray0 + r) * 40 + c8 * 8];
        else        v = (short8v){0,0,0,0,0,0,0,0};
        *(short8v*)&feat64[r][c8 * 8] = v;
    }
    // ---- dir enc -> inp_s cols 512..538 ----
    for (int i = tid; i < 64 * 27; i += 256) {
        int r = i / 27, q = i % 27;
        const float* vd = &viewdirs[(size_t)(ray0 + r) * 3];
        float v;
        if (q < 3)       v = vd[q];
        else if (q < 15) { int ii = q - 3;  v = sinf(vd[ii % 3] * (float)(1 << (ii / 3))); }
        else             { int ii = q - 15; v = cosf(vd[ii % 3] * (float)(1 << (ii / 3))); }
        inp_s[r][512 + q] = f2bf(v);
    }
    for (int i = tid; i < 64 * 13; i += 256) {   // zero pad cols 539..551
        int r = i / 13, c = i % 13;
        inp_s[r][539 + c] = 0;
    }
    __syncthreads();   // the only block-wide barrier

    const int arow  = wv * 16 + (lane & 15);
    const int kseg  = (lane >> 4) * 8;
    const int crow0 = wv * 16 + (lane >> 4) * 4;
    const int ccol  = lane & 15;
    const short8v* d0f = (const short8v*)dw0p;
    const short8v* d1f = (const short8v*)dw1p;
    const short8v* w0f = (const short8v*)w0p;
    const short8v* w1f = (const short8v*)w1p;

    // ---- density layer 0: feats[.,40->64pad] @ dw0 -> h0[64], relu ----
    {
        float4v a0[4];
        #pragma unroll
        for (int nt = 0; nt < 4; ++nt) a0[nt] = (float4v){0.f,0.f,0.f,0.f};
        #pragma unroll
        for (int ks = 0; ks < 2; ++ks) {
            short8v a = *(const short8v*)&feat64[arow][ks*32 + kseg];
            #pragma unroll
            for (int nt = 0; nt < 4; ++nt) {
                short8v b = d0f[(ks*4 + nt) * 64 + lane];
                a0[nt] = __builtin_amdgcn_mfma_f32_16x16x32_bf16(a, b, a0[nt], 0,0,0);
            }
        }
        #pragma unroll
        for (int nt = 0; nt < 4; ++nt) {
            float bias = db0[nt*16 + ccol];
            #pragma unroll
            for (int j = 0; j < 4; ++j)
                feat64[crow0 + j][nt*16 + ccol] = f2bf(fmaxf(a0[nt][j] + bias, 0.0f));
        }
    }

    float4v acc[16];

    // ---- density layer 1: h0[64] @ dw1 -> x[256]; density = softplus(x0-1) ----
    #pragma unroll
    for (int nt = 0; nt < 16; ++nt) acc[nt] = (float4v){0.f,0.f,0.f,0.f};
    #pragma unroll
    for (int ks = 0; ks < 2; ++ks) {
        short8v a = *(const short8v*)&feat64[arow][ks*32 + kseg];
        #pragma unroll
        for (int nt = 0; nt < 16; ++nt) {
            short8v b = d1f[(ks*16 + nt) * 64 + lane];
            acc[nt] = __builtin_amdgcn_mfma_f32_16x16x32_bf16(a, b, acc[nt], 0,0,0);
        }
    }
    #pragma unroll
    for (int nt = 0; nt < 16; ++nt) {
        float bias = db1[nt*16 + ccol];
        #pragma unroll
        for (int j = 0; j < 4; ++j) {
            float x = acc[nt][j] + bias;
            inp_s[crow0 + j][256 + nt*16 + ccol] = f2bf(x);
            if (nt == 0 && ccol == 0) {
                float z = x - 1.0f;   // DENSITY_BIAS
                out[ray0 + crow0 + j] = fmaxf(z, 0.0f) + log1pf(expf(-fabsf(z)));
            }
        }
    }

    // ---- GEMM1: y1 = relu([x,dir] @ sw0 + sb0), K=288 (9 ks) ----
    #pragma unroll
    for (int nt = 0; nt < 16; ++nt) acc[nt] = (float4v){0.f,0.f,0.f,0.f};
    for (int ks = 0; ks < 9; ++ks) {
        short8v a = *(const short8v*)&inp_s[arow][256 + ks*32 + kseg];
        #pragma unroll
        for (int nt = 0; nt < 16; ++nt) {
            short8v b = w0f[(ks*16 + nt) * 64 + lane];
            acc[nt] = __builtin_amdgcn_mfma_f32_16x16x32_bf16(a, b, acc[nt], 0,0,0);
        }
    }
    #pragma unroll
    for (int nt = 0; nt < 16; ++nt) {
        float bias = sb0[nt*16 + ccol];
        #pragma unroll
        for (int j = 0; j < 4; ++j)
            inp_s[crow0 + j][nt*16 + ccol] = f2bf(fmaxf(acc[nt][j] + bias, 0.0f));
    }

    // ---- GEMM2: y2 = relu([y1,x,dir] @ sw1 + sb1), K=544 (17 ks) ----
    #pragma unroll
    for (int nt = 0; nt < 16; ++nt) acc[nt] = (float4v){0.f,0.f,0.f,0.f};
    for (int ks = 0; ks < 17; ++ks) {
        short8v a = *(const short8v*)&inp_s[arow][ks*32 + kseg];
        #pragma unroll
        for (int nt = 0; nt < 16; ++nt) {
            short8v b = w1f[(ks*16 + nt) * 64 + lane];
            acc[nt] = __builtin_amdgcn_mfma_f32_16x16x32_bf16(a, b, acc[nt], 0,0,0);
        }
    }

    // ---- epilogue: y2 = relu(acc + sb1); rgb = sigmoid(y2 @ rw + rb) ----
    {
        float p[4][3];
        #pragma unroll
        for (int j = 0; j < 4; ++j) { p[j][0] = p[j][1] = p[j][2] = 0.f; }
        #pragma unroll
        for (int nt = 0; nt < 16; ++nt) {
            float bias = sb1[nt*16 + ccol];
            const float* rwn = &rw[(size_t)(nt*16 + ccol) * 3];
            float r0 = rwn[0], r1 = rwn[1], r2 = rwn[2];
            #pragma unroll
            for (int j = 0; j < 4; ++j) {
                float y = fmaxf(acc[nt][j] + bias, 0.0f);
                p[j][0] += y * r0; p[j][1] += y * r1; p[j][2] += y * r2;
            }
        }
        #pragma unroll
        for (int m = 1; m <= 8; m <<= 1) {
            #pragma unroll
            for (int j = 0; j < 4; ++j) {
                p[j][0] += __shfl_xor(p[j][0], m);
                p[j][1] += __shfl_xor(p[j][1], m);
                p[j][2] += __shfl_xor(p[j][2], m);
            }
        }
        if ((lane & 15) == 0) {
            #pragma unroll
            for (int j = 0; j < 4; ++j) {
                int ray = ray0 + crow0 + j;
                out[NRAYS + ray * 3 + 0] = sigmoidf_(p[j][0] + rb[0]) * 1.002f - 0.001f;
                out[NRAYS + ray * 3 + 1] = sigmoidf_(p[j][1] + rb[1]) * 1.002f - 0.001f;
                out[NRAYS + ray * 3 + 2] = sigmoidf_(p[j][2] + rb[2]) * 1.002f - 0.001f;
            }
        }
    }
}

// ---------------------------------------------------------------------------
extern "C" void kernel_launch(void* const* d_in, const int* in_sizes, int n_in,
                              void* d_out, int out_size, void* d_ws, size_t ws_size,
                              hipStream_t stream)
{
    const float* means    = (const float*)d_in[0];
    const float* stds     = (const float*)d_in[1];
    const float* viewdirs = (const float*)d_in[2];
    const float* emb      = (const float*)d_in[3];
    const float* dw0      = (const float*)d_in[4];
    const float* db0      = (const float*)d_in[5];
    const float* dw1      = (const float*)d_in[6];
    const float* db1      = (const float*)d_in[7];
    const float* sw0      = (const float*)d_in[8];
    const float* sb0      = (const float*)d_in[9];
    const float* sw1      = (const float*)d_in[10];
    const float* sb1      = (const float*)d_in[11];
    const float* rw       = (const float*)d_in[12];
    const float* rb       = (const float*)d_in[13];

    float* out = (float*)d_out;
    char*  ws  = (char*)d_ws;

    // ws layout (bytes, 16-aligned)
    short* feat_bf = (short*)(ws);               // 32768*40*2 = 2,621,440
    short* dw0p    = (short*)(ws + 2621440);     //   8,192
    short* dw1p    = (short*)(ws + 2629632);     //  32,768
    short* w0p     = (short*)(ws + 2662400);     // 147,456
    short* w1p     = (short*)(ws + 2809856);     // 278,528   (end 3,088,384)

    pack4<<<(PN0+PN1+PN2+PN3 + 255) / 256, 256, 0, stream>>>(
        dw0, dw1, sw0, sw1, dw0p, dw1p, w0p, w1p);
    enc_kernel<<<NRAYS / 64, 768, 0, stream>>>(means, stds, emb, feat_bf);
    mlp_kernel<<<NRAYS / 64, 256, 0, stream>>>(
        feat_bf, viewdirs, dw0p, db0, dw1p, db1, w0p, sb0, w1p, sb1, rw, rb, out);
}